// Round 8
// baseline (5812.674 us; speedup 1.0000x reference)
//
#include <hip/hip_runtime.h>
#include <hip/hip_bf16.h>

typedef __attribute__((ext_vector_type(8))) short short8;
typedef __attribute__((ext_vector_type(4))) float f32x4;

#define B_ 64
#define S_ 1024
#define I_ 256
#define H_ 512
#define O_ 256
#define M_ (B_ * S_)   // 65536 rows everywhere
#define SC 2.8853900817779268f   // 2*log2(e), folded into U_w, W_w, cbias
#define NPIN 9                   // W k-slices pinned in regs; 16-NPIN streamed from L2

// ---------- helpers ----------
__device__ __forceinline__ ushort bf16_rne(float f) {
  unsigned u = __float_as_uint(f);
  return (ushort)((u + 0x7FFFu + ((u >> 16) & 1u)) >> 16);
}
__device__ __forceinline__ float bf16_f(ushort s) {
  return __uint_as_float(((unsigned)s) << 16);
}
__device__ __forceinline__ unsigned cvt_pk_bf16(float lo, float hi) {
  unsigned r;
  asm("v_cvt_pk_bf16_f32 %0, %1, %2" : "=v"(r) : "v"(lo), "v"(hi));
  return r;
}
__device__ __forceinline__ void gll16(const void* g, void* l) {
  __builtin_amdgcn_global_load_lds((const __attribute__((address_space(1))) void*)g,
                                   (__attribute__((address_space(3))) void*)l, 16, 0, 0);
}
// tanh(a/SC) where a is pre-scaled by SC = 2*log2(e): t = 2^a; tanh = (t-1)/(t+1)
__device__ __forceinline__ float tanh_pre(float a) {
#if __has_builtin(__builtin_amdgcn_exp2f)
  float t = __builtin_amdgcn_exp2f(fminf(a, 26.0f));
#else
  float t = exp2f(fminf(a, 26.0f));
#endif
#if __has_builtin(__builtin_amdgcn_rcpf)
  return (t - 1.0f) * __builtin_amdgcn_rcpf(t + 1.0f);
#else
  return (t - 1.0f) / (t + 1.0f);
#endif
}

// ---------- fp32 -> bf16 convert (with scale) ----------
__global__ void cvt_kern(const float* __restrict__ in, ushort* __restrict__ out, long n,
                         float scale) {
  long i = ((long)blockIdx.x * blockDim.x + threadIdx.x) * 4;
  const long stride = (long)gridDim.x * blockDim.x * 4;
  for (; i < n; i += stride) {
    const float4 v = *(const float4*)(in + i);
    ushort4 o;
    o.x = bf16_rne(v.x * scale); o.y = bf16_rne(v.y * scale);
    o.z = bf16_rne(v.z * scale); o.w = bf16_rne(v.w * scale);
    *(ushort4*)(out + i) = o;
  }
}

__global__ void biascomb_kern(const float* __restrict__ a, const float* __restrict__ b,
                              float* __restrict__ o) {
  int i = threadIdx.x;
  o[i] = (a[i] + b[i]) * SC;
}

// ---------- small fp32 GEMM: C[M,N] = A[M,K] @ B[K,N], row-major ----------
__global__ __launch_bounds__(256) void f32gemm_kern(
    const float* __restrict__ A, const float* __restrict__ Bm,
    float* __restrict__ C, int M, int N, int K)
{
  __shared__ float As[16][16];
  __shared__ float Bs[16][17];
  const int tx = threadIdx.x & 15, ty = threadIdx.x >> 4;
  const int row = blockIdx.y * 16 + ty, col = blockIdx.x * 16 + tx;
  float acc = 0.0f;
  for (int k0 = 0; k0 < K; k0 += 16) {
    As[ty][tx] = A[(size_t)row * K + k0 + tx];
    Bs[ty][tx] = Bm[(size_t)(k0 + ty) * N + col];
    __syncthreads();
    #pragma unroll
    for (int kk = 0; kk < 16; ++kk) acc += As[ty][kk] * Bs[kk][tx];
    __syncthreads();
  }
  C[(size_t)row * N + col] = acc;
}

// ---------- matvec: y = M@x + b (fp32), one wave per row, shuffle reduce ----------
__global__ void matvec_kern(const float* __restrict__ Mw, const float* __restrict__ x,
                            const float* __restrict__ b, float* __restrict__ y, int R, int C) {
  const int wid = (int)((blockIdx.x * blockDim.x + threadIdx.x) >> 6);
  const int lane = threadIdx.x & 63;
  if (wid >= R) return;
  float acc = 0.0f;
  for (int k = lane; k < C; k += 64) acc += Mw[(size_t)wid * C + k] * x[k];
  #pragma unroll
  for (int off = 32; off; off >>= 1) acc += __shfl_down(acc, off, 64);
  if (lane == 0) y[wid] = acc + b[wid];
}

// ---------- GEMM: C[M,N] = A[M,K] @ Wt[N,K]^T + bias ----------
template<bool OUT_F32>
__global__ __launch_bounds__(256) void gemm_kern(
    const ushort* __restrict__ A, const ushort* __restrict__ Wt,
    const float* __restrict__ bias, void* __restrict__ out,
    int M, int N, int K)
{
  __shared__ char smem[16384];
  const int tid = threadIdx.x;
  const int lane = tid & 63, wave = tid >> 6;
  const int wm = wave >> 1, wn = wave & 1;
  const int nt = N >> 7;
  const int bm = blockIdx.x / nt, bn = blockIdx.x % nt;
  const long m0 = (long)bm * 128, n0 = (long)bn * 128;

  f32x4 acc[4][4] = {};
  const int KT = K >> 5;
  for (int kt = 0; kt < KT; ++kt) {
    #pragma unroll
    for (int i = 0; i < 4; ++i) {
      const int c = wave * 4 + i;
      const int isB = c >> 3;
      const int cc = c & 7;
      const int kgrp = cc >> 1, rhalf = cc & 1;
      const int row = rhalf * 64 + lane;
      const ushort* src = (isB ? Wt + (n0 + row) * (long)K : A + (m0 + row) * (long)K)
                          + (long)kt * 32 + kgrp * 8;
      gll16(src, smem + isB * 8192 + kgrp * 2048 + rhalf * 1024);
    }
    __syncthreads();
    const char* Ab = smem + (lane >> 4) * 2048;
    const char* Bb = smem + 8192 + (lane >> 4) * 2048;
    short8 af[4], bf[4];
    #pragma unroll
    for (int i = 0; i < 4; ++i) {
      af[i] = *(const short8*)(Ab + (wm * 64 + i * 16 + (lane & 15)) * 16);
      bf[i] = *(const short8*)(Bb + (wn * 64 + i * 16 + (lane & 15)) * 16);
    }
    #pragma unroll
    for (int mi = 0; mi < 4; ++mi)
      #pragma unroll
      for (int ni = 0; ni < 4; ++ni)
        acc[mi][ni] = __builtin_amdgcn_mfma_f32_16x16x32_bf16(af[mi], bf[ni], acc[mi][ni], 0, 0, 0);
    __syncthreads();
  }
  #pragma unroll
  for (int ni = 0; ni < 4; ++ni) {
    const long n = n0 + wn * 64 + ni * 16 + (lane & 15);
    const float bv = bias[n];
    #pragma unroll
    for (int mi = 0; mi < 4; ++mi) {
      const long mrow = m0 + wm * 64 + mi * 16 + (lane >> 4) * 4;
      #pragma unroll
      for (int r = 0; r < 4; ++r) {
        const float v = acc[mi][ni][r] + bv;
        if (OUT_F32) ((float*)out)[(mrow + r) * (long)N + n] = v;
        else         ((ushort*)out)[(mrow + r) * (long)N + n] = bf16_rne(v);
      }
    }
  }
}

// ---------- recurrence: h_t = tanh(xu_t + W h_{t-1}) (args pre-scaled by SC) ----------
// r7 structure (2322us) with ONE structural delta: W-LDS eliminated.
// 4 WGs x 16 batches, 512 threads = 8 waves (2/SIMD), 4 m-tiles/wave.
// W k-slices 0..8 pinned in regs (144); slices 9..15 STREAMED from global (L2-
// resident, VMEM pipe) each step: slices 9,10 prefetched at step top, slice s+2
// issued at group s (<=3 slices in flight). LDS = h ping-pong only (32KB);
// h-read traffic unchanged (128 b128/CU/step); W-LDS reads: 128 -> 0.
__global__ __launch_bounds__(512, 2) void rec_kern(
    const ushort* __restrict__ XU,   // [B*S, H] bf16, SC-scaled; row = b*S + t
    const ushort* __restrict__ Wb,   // [H, H] bf16 row-major, SC-scaled
    ushort* __restrict__ Hst)        // [B*S, H] bf16 (unscaled h)
{
  extern __shared__ char smem[];     // [0,32K): h ping-pong
  const int tid = threadIdx.x;
  const int lane = tid & 63;
  const int wave = tid >> 6;         // 0..7
  const int b = lane & 15;
  const int hi = lane >> 4;          // 0..3
  const int bg = blockIdx.x << 4;
  const int swz = (b & 7) << 4;      // r2 swizzle (empirically best)

  // zero both h buffers (h_{-1} = 0 in buf 0)
  {
    f32x4 zz = 0.0f;
    *(f32x4*)(smem + tid * 64) = zz;
    *(f32x4*)(smem + tid * 64 + 16) = zz;
    *(f32x4*)(smem + tid * 64 + 32) = zz;
    *(f32x4*)(smem + tid * 64 + 48) = zz;
  }
  // W registers: slices 0..NPIN-1 for this wave's 4 m-tiles, pinned live via asm
  short8 wreg[4][NPIN];
  #pragma unroll
  for (int mt = 0; mt < 4; ++mt) {
    const int mtg = wave * 4 + mt;
    const ushort* wrow = Wb + (size_t)(mtg * 16 + b) * H_ + hi * 8;
    #pragma unroll
    for (int s = 0; s < NPIN; ++s)
      wreg[mt][s] = *(const short8*)(wrow + s * 32);
  }
  #pragma unroll
  for (int mt = 0; mt < 4; ++mt)
    #pragma unroll
    for (int s = 0; s < NPIN; ++s)
      asm volatile("" : "+v"(wreg[mt][s]));
  // streamed-W base pointers (constant across steps; imm offsets select slice)
  const ushort* wmt[4];
  #pragma unroll
  for (int mt = 0; mt < 4; ++mt)
    wmt[mt] = Wb + (size_t)((wave * 4 + mt) * 16 + b) * H_ + hi * 8;
  __syncthreads();

  const ushort* xup = XU + (size_t)(bg + b) * S_ * H_ + wave * 64 + hi * 4;
  ushort* hgp = Hst + (size_t)(bg + b) * S_ * H_ + wave * 64 + hi * 4;
  const int hoff = b * 1024;                     // within h buffer
  const int woff = (wave * 128 + hi * 8);        // epilogue LDS write base (bytes, pre-XOR)

  for (int t = 0; t < S_; ++t) {
    // xu loads first (consumed last, in the epilogue)
    uint2 xu[4];
    #pragma unroll
    for (int mt = 0; mt < 4; ++mt)
      xu[mt] = *(const uint2*)(xup + mt * 16);
    xup += H_;

    // prefetch streamed W slices NPIN, NPIN+1 (consumed at groups 9,10)
    short8 ws[16 - NPIN][4];
    #pragma unroll
    for (int mt = 0; mt < 4; ++mt) ws[0][mt] = *(const short8*)(wmt[mt] + NPIN * 32);
    #pragma unroll
    for (int mt = 0; mt < 4; ++mt) ws[1][mt] = *(const short8*)(wmt[mt] + (NPIN + 1) * 32);

    const char* hb = smem + (t & 1) * 16384 + hoff;    // h_{t-1}
    f32x4 acc[4] = {};
    #pragma unroll
    for (int s = 0; s < 16; ++s) {
      // JIT-issue slice s+2 (keeps <=3 streamed slices in flight);
      // sched_barrier blocks only VMEM motion so loads can't be hoisted en masse
      if (s >= NPIN && s + 2 < 16) {
        __builtin_amdgcn_sched_barrier(0x38F);
        #pragma unroll
        for (int mt = 0; mt < 4; ++mt)
          ws[s + 2 - NPIN][mt] = *(const short8*)(wmt[mt] + (s + 2) * 32);
      }
      const short8 bfrag = *(const short8*)(hb + ((s * 64 + hi * 16) ^ swz));
      #pragma unroll
      for (int mt = 0; mt < 4; ++mt) {
        const short8 w = (s < NPIN) ? wreg[mt][s] : ws[s - NPIN][mt];
        acc[mt] = __builtin_amdgcn_mfma_f32_16x16x32_bf16(w, bfrag, acc[mt], 0, 0, 0);
      }
    }
    // epilogue: h_t = tanh_pre(acc + xu), cvt_pk pack, LDS + global store
    char* hw = smem + ((t + 1) & 1) * 16384 + hoff;
    #pragma unroll
    for (int mt = 0; mt < 4; ++mt) {
      const float h0 = tanh_pre(acc[mt][0] + bf16_f((ushort)(xu[mt].x & 0xFFFFu)));
      const float h1 = tanh_pre(acc[mt][1] + bf16_f((ushort)(xu[mt].x >> 16)));
      const float h2 = tanh_pre(acc[mt][2] + bf16_f((ushort)(xu[mt].y & 0xFFFFu)));
      const float h3 = tanh_pre(acc[mt][3] + bf16_f((ushort)(xu[mt].y >> 16)));
      uint2 hv;
      hv.x = cvt_pk_bf16(h0, h1);
      hv.y = cvt_pk_bf16(h2, h3);
      *(uint2*)(hw + ((woff + mt * 32) ^ swz)) = hv;   // h for next step
      *(uint2*)(hgp + mt * 16) = hv;                   // h for head GEMM
    }
    hgp += H_;
    __syncthreads();  // h_t visible (and h_{t-1} reads done) before next step
  }
}

// ---------- launcher ----------
extern "C" void kernel_launch(void* const* d_in, const int* in_sizes, int n_in,
                              void* d_out, int out_size, void* d_ws, size_t ws_size,
                              hipStream_t stream) {
  const float* x     = (const float*)d_in[0];
  const float* U_w   = (const float*)d_in[1];
  const float* U_b   = (const float*)d_in[2];
  const float* W_w   = (const float*)d_in[3];
  const float* W_b   = (const float*)d_in[4];
  const float* V_w   = (const float*)d_in[5];
  const float* V_b   = (const float*)d_in[6];
  const float* fc1_w = (const float*)d_in[7];
  const float* fc1_b = (const float*)d_in[8];
  const float* fc2_w = (const float*)d_in[9];
  const float* fc2_b = (const float*)d_in[10];
  const float* fc3_w = (const float*)d_in[11];
  const float* fc3_b = (const float*)d_in[12];

  char* ws = (char*)d_ws;
  // ws layout: [0,64M): Hst   [64M,96M): x_bf16   [128M, +~4M): weights/scratch
  ushort* Hst  = (ushort*)ws;                               // 67,108,864 B
  ushort* xb16 = (ushort*)(ws + 67108864);                  // 33,554,432 B
  char*   wb   = ws + 134217728;
  ushort* U_wb = (ushort*)wb;                    // 512*256  (SC-scaled)
  ushort* W_wb = U_wb + 131072;                  // 512*512  (SC-scaled)
  ushort* Wcb  = W_wb + 262144;                  // 256*512
  float*  C1   = (float*)(Wcb + 131072);         // 512*512 f32
  float*  C2   = C1 + 262144;                    // 512*512 f32
  float*  Wcf  = C2 + 262144;                    // 256*512 f32
  float*  cbias = Wcf + 131072;                  // 512 f32 (SC-scaled)
  float*  t1   = cbias + 512;                    // 512 f32
  float*  t2   = t1 + 512;                       // 512 f32
  float*  bc   = t2 + 512;                       // 256 f32
  ushort* bufA = (ushort*)d_out;                 // XU scratch (bf16), then fp32 out

  // bf16 staging converts (U_w, W_w, cbias pre-scaled by SC = 2*log2e)
  cvt_kern<<<2048, 256, 0, stream>>>(x, xb16, (long)M_ * I_, 1.0f);
  cvt_kern<<<128, 256, 0, stream>>>(U_w, U_wb, (long)H_ * I_, SC);
  cvt_kern<<<256, 256, 0, stream>>>(W_w, W_wb, (long)H_ * H_, SC);
  biascomb_kern<<<1, 512, 0, stream>>>(U_b, W_b, cbias);

  // fused head weights (fp32): C1 = fc1@V, C2 = fc2@C1, Wc = fc3@C2
  f32gemm_kern<<<dim3(32, 32), 256, 0, stream>>>(fc1_w, V_w, C1, H_, H_, H_);
  f32gemm_kern<<<dim3(32, 32), 256, 0, stream>>>(fc2_w, C1, C2, H_, H_, H_);
  f32gemm_kern<<<dim3(32, 16), 256, 0, stream>>>(fc3_w, C2, Wcf, O_, H_, H_);
  // bias chain: bc = fc3@(fc2@(fc1@V_b + b1) + b2) + b3  (wave-per-row matvecs)
  matvec_kern<<<128, 256, 0, stream>>>(fc1_w, V_b, fc1_b, t1, H_, H_);
  matvec_kern<<<128, 256, 0, stream>>>(fc2_w, t1, fc2_b, t2, H_, H_);
  matvec_kern<<<64, 256, 0, stream>>>(fc3_w, t2, fc3_b, bc, O_, H_);
  cvt_kern<<<128, 256, 0, stream>>>(Wcf, Wcb, (long)O_ * H_, 1.0f);

  // XU = x @ (SC*U^T) + SC*(U_b + W_b)   -> bufA (d_out as bf16 scratch)
  gemm_kern<false><<<dim3(512 * 4), 256, 0, stream>>>(xb16, U_wb, cbias, bufA, M_, H_, I_);

  // recurrence -> Hst
  hipFuncSetAttribute((const void*)rec_kern, hipFuncAttributeMaxDynamicSharedMemorySize, 32768);
  rec_kern<<<dim3(4), dim3(512), 32768, stream>>>(bufA, W_wb, Hst);

  // head: out = Hst @ Wc^T + bc -> d_out fp32 [B,S,O]
  gemm_kern<true><<<dim3(512 * 2), 256, 0, stream>>>(Hst, Wcb, bc, d_out, M_, O_, H_);

  (void)in_sizes; (void)n_in; (void)out_size; (void)ws_size;
}

// Round 9
// 4272.124 us; speedup vs baseline: 1.3606x; 1.3606x over previous
//
#include <hip/hip_runtime.h>
#include <hip/hip_bf16.h>

typedef __attribute__((ext_vector_type(8))) short short8;
typedef __attribute__((ext_vector_type(4))) float f32x4;

#define B_ 64
#define S_ 1024
#define I_ 256
#define H_ 512
#define O_ 256
#define M_ (B_ * S_)   // 65536 rows everywhere
#define SC 2.8853900817779268f   // 2*log2(e), folded into U_w, W_w, cbias
#define NPIN 14                  // W k-slices pinned in regs; 16-NPIN from LDS

// ---------- helpers ----------
__device__ __forceinline__ ushort bf16_rne(float f) {
  unsigned u = __float_as_uint(f);
  return (ushort)((u + 0x7FFFu + ((u >> 16) & 1u)) >> 16);
}
__device__ __forceinline__ float bf16_f(ushort s) {
  return __uint_as_float(((unsigned)s) << 16);
}
__device__ __forceinline__ unsigned cvt_pk_bf16(float lo, float hi) {
  unsigned r;
  asm("v_cvt_pk_bf16_f32 %0, %1, %2" : "=v"(r) : "v"(lo), "v"(hi));
  return r;
}
__device__ __forceinline__ void gll16(const void* g, void* l) {
  __builtin_amdgcn_global_load_lds((const __attribute__((address_space(1))) void*)g,
                                   (__attribute__((address_space(3))) void*)l, 16, 0, 0);
}
// tanh(a/SC) where a is pre-scaled by SC = 2*log2(e): t = 2^a; tanh = (t-1)/(t+1)
__device__ __forceinline__ float tanh_pre(float a) {
#if __has_builtin(__builtin_amdgcn_exp2f)
  float t = __builtin_amdgcn_exp2f(fminf(a, 26.0f));
#else
  float t = exp2f(fminf(a, 26.0f));
#endif
#if __has_builtin(__builtin_amdgcn_rcpf)
  return (t - 1.0f) * __builtin_amdgcn_rcpf(t + 1.0f);
#else
  return (t - 1.0f) / (t + 1.0f);
#endif
}

// ---------- fp32 -> bf16 convert (with scale) ----------
__global__ void cvt_kern(const float* __restrict__ in, ushort* __restrict__ out, long n,
                         float scale) {
  long i = ((long)blockIdx.x * blockDim.x + threadIdx.x) * 4;
  const long stride = (long)gridDim.x * blockDim.x * 4;
  for (; i < n; i += stride) {
    const float4 v = *(const float4*)(in + i);
    ushort4 o;
    o.x = bf16_rne(v.x * scale); o.y = bf16_rne(v.y * scale);
    o.z = bf16_rne(v.z * scale); o.w = bf16_rne(v.w * scale);
    *(ushort4*)(out + i) = o;
  }
}

__global__ void biascomb_kern(const float* __restrict__ a, const float* __restrict__ b,
                              float* __restrict__ o) {
  int i = threadIdx.x;
  o[i] = (a[i] + b[i]) * SC;
}

// ---------- small fp32 GEMM: C[M,N] = A[M,K] @ B[K,N], row-major ----------
__global__ __launch_bounds__(256) void f32gemm_kern(
    const float* __restrict__ A, const float* __restrict__ Bm,
    float* __restrict__ C, int M, int N, int K)
{
  __shared__ float As[16][16];
  __shared__ float Bs[16][17];
  const int tx = threadIdx.x & 15, ty = threadIdx.x >> 4;
  const int row = blockIdx.y * 16 + ty, col = blockIdx.x * 16 + tx;
  float acc = 0.0f;
  for (int k0 = 0; k0 < K; k0 += 16) {
    As[ty][tx] = A[(size_t)row * K + k0 + tx];
    Bs[ty][tx] = Bm[(size_t)(k0 + ty) * N + col];
    __syncthreads();
    #pragma unroll
    for (int kk = 0; kk < 16; ++kk) acc += As[ty][kk] * Bs[kk][tx];
    __syncthreads();
  }
  C[(size_t)row * N + col] = acc;
}

// ---------- matvec: y = M@x + b (fp32), one wave per row, shuffle reduce ----------
__global__ void matvec_kern(const float* __restrict__ Mw, const float* __restrict__ x,
                            const float* __restrict__ b, float* __restrict__ y, int R, int C) {
  const int wid = (int)((blockIdx.x * blockDim.x + threadIdx.x) >> 6);
  const int lane = threadIdx.x & 63;
  if (wid >= R) return;
  float acc = 0.0f;
  for (int k = lane; k < C; k += 64) acc += Mw[(size_t)wid * C + k] * x[k];
  #pragma unroll
  for (int off = 32; off; off >>= 1) acc += __shfl_down(acc, off, 64);
  if (lane == 0) y[wid] = acc + b[wid];
}

// ---------- GEMM: C[M,N] = A[M,K] @ Wt[N,K]^T + bias ----------
template<bool OUT_F32>
__global__ __launch_bounds__(256) void gemm_kern(
    const ushort* __restrict__ A, const ushort* __restrict__ Wt,
    const float* __restrict__ bias, void* __restrict__ out,
    int M, int N, int K)
{
  __shared__ char smem[16384];
  const int tid = threadIdx.x;
  const int lane = tid & 63, wave = tid >> 6;
  const int wm = wave >> 1, wn = wave & 1;
  const int nt = N >> 7;
  const int bm = blockIdx.x / nt, bn = blockIdx.x % nt;
  const long m0 = (long)bm * 128, n0 = (long)bn * 128;

  f32x4 acc[4][4] = {};
  const int KT = K >> 5;
  for (int kt = 0; kt < KT; ++kt) {
    #pragma unroll
    for (int i = 0; i < 4; ++i) {
      const int c = wave * 4 + i;
      const int isB = c >> 3;
      const int cc = c & 7;
      const int kgrp = cc >> 1, rhalf = cc & 1;
      const int row = rhalf * 64 + lane;
      const ushort* src = (isB ? Wt + (n0 + row) * (long)K : A + (m0 + row) * (long)K)
                          + (long)kt * 32 + kgrp * 8;
      gll16(src, smem + isB * 8192 + kgrp * 2048 + rhalf * 1024);
    }
    __syncthreads();
    const char* Ab = smem + (lane >> 4) * 2048;
    const char* Bb = smem + 8192 + (lane >> 4) * 2048;
    short8 af[4], bf[4];
    #pragma unroll
    for (int i = 0; i < 4; ++i) {
      af[i] = *(const short8*)(Ab + (wm * 64 + i * 16 + (lane & 15)) * 16);
      bf[i] = *(const short8*)(Bb + (wn * 64 + i * 16 + (lane & 15)) * 16);
    }
    #pragma unroll
    for (int mi = 0; mi < 4; ++mi)
      #pragma unroll
      for (int ni = 0; ni < 4; ++ni)
        acc[mi][ni] = __builtin_amdgcn_mfma_f32_16x16x32_bf16(af[mi], bf[ni], acc[mi][ni], 0, 0, 0);
    __syncthreads();
  }
  #pragma unroll
  for (int ni = 0; ni < 4; ++ni) {
    const long n = n0 + wn * 64 + ni * 16 + (lane & 15);
    const float bv = bias[n];
    #pragma unroll
    for (int mi = 0; mi < 4; ++mi) {
      const long mrow = m0 + wm * 64 + mi * 16 + (lane >> 4) * 4;
      #pragma unroll
      for (int r = 0; r < 4; ++r) {
        const float v = acc[mi][ni][r] + bv;
        if (OUT_F32) ((float*)out)[(mrow + r) * (long)N + n] = v;
        else         ((ushort*)out)[(mrow + r) * (long)N + n] = bf16_rne(v);
      }
    }
  }
}

// ---------- recurrence: h_t = tanh(xu_t + W h_{t-1}) (args pre-scaled by SC) ----------
// r7 structure (anchor: rec 2322us) with ONE delta: NPIN 12 -> 14.
// 4 WGs x 16 batches, 512 threads = 8 waves (2/SIMD), 4 m-tiles/wave.
// W k-slices 0..13 pinned via asm (224 regs/wave; compiler migrates to AGPRs,
// total ~290/wave < r2's proven 320 envelope). Slices 14..15 in LDS (64KB).
// Per-wave W-LDS reads 16 -> 8; per-CU LDS b128 ops 256 -> 192 per step.
// h ping-pong [2][16][512] bf16 (32KB), swz=(b&7)<<4 (r6: empirically best).
// W NEVER on the vmcnt path inside the MFMA phase (r8 lesson).
__global__ __launch_bounds__(512, 2) void rec_kern(
    const ushort* __restrict__ XU,   // [B*S, H] bf16, SC-scaled; row = b*S + t
    const ushort* __restrict__ Wb,   // [H, H] bf16 row-major, SC-scaled
    ushort* __restrict__ Hst)        // [B*S, H] bf16 (unscaled h)
{
  extern __shared__ char smem[];     // [0,32K): h pingpong  [32K,96K): W slices 14,15
  const int tid = threadIdx.x;
  const int lane = tid & 63;
  const int wave = tid >> 6;         // 0..7
  const int b = lane & 15;
  const int hi = lane >> 4;          // 0..3
  const int bg = blockIdx.x << 4;
  const int swz = (b & 7) << 4;      // r2 swizzle (empirically best)

  // stage W slices 14..15 -> LDS fragments [(s-14)][mt][lane*16]
  #pragma unroll
  for (int i = 0; i < 8; ++i) {
    const int ch = wave * 8 + i;           // 0..63
    const int s = 14 + (ch >> 5);
    const int mt = ch & 31;
    const ushort* src = Wb + (size_t)(mt * 16 + b) * H_ + s * 32 + hi * 8;
    gll16(src, smem + 32768 + (size_t)(s - 14) * 32768 + mt * 1024);
  }
  // zero both h buffers (h_{-1} = 0 in buf 0)
  {
    f32x4 zz = 0.0f;
    *(f32x4*)(smem + tid * 64) = zz;
    *(f32x4*)(smem + tid * 64 + 16) = zz;
    *(f32x4*)(smem + tid * 64 + 32) = zz;
    *(f32x4*)(smem + tid * 64 + 48) = zz;
  }
  // W registers: slices 0..13 for this wave's 4 m-tiles, pinned live via asm
  short8 wreg[4][NPIN];
  #pragma unroll
  for (int mt = 0; mt < 4; ++mt) {
    const int mtg = wave * 4 + mt;
    const ushort* wrow = Wb + (size_t)(mtg * 16 + b) * H_ + hi * 8;
    #pragma unroll
    for (int s = 0; s < NPIN; ++s)
      wreg[mt][s] = *(const short8*)(wrow + s * 32);
  }
  #pragma unroll
  for (int mt = 0; mt < 4; ++mt)
    #pragma unroll
    for (int s = 0; s < NPIN; ++s)
      asm volatile("" : "+v"(wreg[mt][s]));
  __syncthreads();

  const ushort* xup = XU + (size_t)(bg + b) * S_ * H_ + wave * 64 + hi * 4;
  ushort* hgp = Hst + (size_t)(bg + b) * S_ * H_ + wave * 64 + hi * 4;
  const int hoff = b * 1024;                     // within h buffer
  const int woff = (wave * 128 + hi * 8);        // epilogue LDS write base (bytes, pre-XOR)

  for (int t = 0; t < S_; ++t) {
    // issue xu loads now; consumed in the epilogue (~2k cycles later)
    uint2 xu[4];
    #pragma unroll
    for (int mt = 0; mt < 4; ++mt)
      xu[mt] = *(const uint2*)(xup + mt * 16);
    xup += H_;

    const char* hb = smem + (t & 1) * 16384 + hoff;    // h_{t-1}
    f32x4 acc[4] = {};
    #pragma unroll
    for (int s = 0; s < 16; ++s) {
      const short8 bfrag = *(const short8*)(hb + ((s * 64 + hi * 16) ^ swz));
      #pragma unroll
      for (int mt = 0; mt < 4; ++mt) {
        short8 w;
        if (s < NPIN) w = wreg[mt][s];
        else w = *(const short8*)(smem + 32768 + (s - 14) * 32768 + (wave * 4 + mt) * 1024 + lane * 16);
        acc[mt] = __builtin_amdgcn_mfma_f32_16x16x32_bf16(w, bfrag, acc[mt], 0, 0, 0);
      }
    }
    // epilogue: h_t = tanh_pre(acc + xu), cvt_pk pack, LDS + global store
    char* hw = smem + ((t + 1) & 1) * 16384 + hoff;
    #pragma unroll
    for (int mt = 0; mt < 4; ++mt) {
      const float h0 = tanh_pre(acc[mt][0] + bf16_f((ushort)(xu[mt].x & 0xFFFFu)));
      const float h1 = tanh_pre(acc[mt][1] + bf16_f((ushort)(xu[mt].x >> 16)));
      const float h2 = tanh_pre(acc[mt][2] + bf16_f((ushort)(xu[mt].y & 0xFFFFu)));
      const float h3 = tanh_pre(acc[mt][3] + bf16_f((ushort)(xu[mt].y >> 16)));
      uint2 hv;
      hv.x = cvt_pk_bf16(h0, h1);
      hv.y = cvt_pk_bf16(h2, h3);
      *(uint2*)(hw + ((woff + mt * 32) ^ swz)) = hv;   // h for next step
      *(uint2*)(hgp + mt * 16) = hv;                   // h for head GEMM
    }
    hgp += H_;
    __syncthreads();  // h_t visible (and h_{t-1} reads done) before next step
  }
}

// ---------- launcher ----------
extern "C" void kernel_launch(void* const* d_in, const int* in_sizes, int n_in,
                              void* d_out, int out_size, void* d_ws, size_t ws_size,
                              hipStream_t stream) {
  const float* x     = (const float*)d_in[0];
  const float* U_w   = (const float*)d_in[1];
  const float* U_b   = (const float*)d_in[2];
  const float* W_w   = (const float*)d_in[3];
  const float* W_b   = (const float*)d_in[4];
  const float* V_w   = (const float*)d_in[5];
  const float* V_b   = (const float*)d_in[6];
  const float* fc1_w = (const float*)d_in[7];
  const float* fc1_b = (const float*)d_in[8];
  const float* fc2_w = (const float*)d_in[9];
  const float* fc2_b = (const float*)d_in[10];
  const float* fc3_w = (const float*)d_in[11];
  const float* fc3_b = (const float*)d_in[12];

  char* ws = (char*)d_ws;
  // ws layout: [0,64M): Hst   [64M,96M): x_bf16   [128M, +~4M): weights/scratch
  ushort* Hst  = (ushort*)ws;                               // 67,108,864 B
  ushort* xb16 = (ushort*)(ws + 67108864);                  // 33,554,432 B
  char*   wb   = ws + 134217728;
  ushort* U_wb = (ushort*)wb;                    // 512*256  (SC-scaled)
  ushort* W_wb = U_wb + 131072;                  // 512*512  (SC-scaled)
  ushort* Wcb  = W_wb + 262144;                  // 256*512
  float*  C1   = (float*)(Wcb + 131072);         // 512*512 f32
  float*  C2   = C1 + 262144;                    // 512*512 f32
  float*  Wcf  = C2 + 262144;                    // 256*512 f32
  float*  cbias = Wcf + 131072;                  // 512 f32 (SC-scaled)
  float*  t1   = cbias + 512;                    // 512 f32
  float*  t2   = t1 + 512;                       // 512 f32
  float*  bc   = t2 + 512;                       // 256 f32
  ushort* bufA = (ushort*)d_out;                 // XU scratch (bf16), then fp32 out

  // bf16 staging converts (U_w, W_w, cbias pre-scaled by SC = 2*log2e)
  cvt_kern<<<2048, 256, 0, stream>>>(x, xb16, (long)M_ * I_, 1.0f);
  cvt_kern<<<128, 256, 0, stream>>>(U_w, U_wb, (long)H_ * I_, SC);
  cvt_kern<<<256, 256, 0, stream>>>(W_w, W_wb, (long)H_ * H_, SC);
  biascomb_kern<<<1, 512, 0, stream>>>(U_b, W_b, cbias);

  // fused head weights (fp32): C1 = fc1@V, C2 = fc2@C1, Wc = fc3@C2
  f32gemm_kern<<<dim3(32, 32), 256, 0, stream>>>(fc1_w, V_w, C1, H_, H_, H_);
  f32gemm_kern<<<dim3(32, 32), 256, 0, stream>>>(fc2_w, C1, C2, H_, H_, H_);
  f32gemm_kern<<<dim3(32, 16), 256, 0, stream>>>(fc3_w, C2, Wcf, O_, H_, H_);
  // bias chain: bc = fc3@(fc2@(fc1@V_b + b1) + b2) + b3  (wave-per-row matvecs)
  matvec_kern<<<128, 256, 0, stream>>>(fc1_w, V_b, fc1_b, t1, H_, H_);
  matvec_kern<<<128, 256, 0, stream>>>(fc2_w, t1, fc2_b, t2, H_, H_);
  matvec_kern<<<64, 256, 0, stream>>>(fc3_w, t2, fc3_b, bc, O_, H_);
  cvt_kern<<<128, 256, 0, stream>>>(Wcf, Wcb, (long)O_ * H_, 1.0f);

  // XU = x @ (SC*U^T) + SC*(U_b + W_b)   -> bufA (d_out as bf16 scratch)
  gemm_kern<false><<<dim3(512 * 4), 256, 0, stream>>>(xb16, U_wb, cbias, bufA, M_, H_, I_);

  // recurrence -> Hst
  hipFuncSetAttribute((const void*)rec_kern, hipFuncAttributeMaxDynamicSharedMemorySize, 98304);
  rec_kern<<<dim3(4), dim3(512), 98304, stream>>>(bufA, W_wb, Hst);

  // head: out = Hst @ Wc^T + bc -> d_out fp32 [B,S,O]
  gemm_kern<true><<<dim3(512 * 2), 256, 0, stream>>>(Hst, Wcb, bc, d_out, M_, O_, H_);

  (void)in_sizes; (void)n_in; (void)out_size; (void)ws_size;
}

// Round 10
// 2855.202 us; speedup vs baseline: 2.0358x; 1.4963x over previous
//
#include <hip/hip_runtime.h>
#include <hip/hip_bf16.h>

typedef __attribute__((ext_vector_type(8))) short short8;
typedef __attribute__((ext_vector_type(4))) float f32x4;

#define B_ 64
#define S_ 1024
#define I_ 256
#define H_ 512
#define O_ 256
#define M_ (B_ * S_)   // 65536 rows everywhere
#define SC 2.8853900817779268f   // 2*log2(e), folded into U_w, W_w, cbias
#define NPIN 12                  // W k-slices pinned in regs (PROVEN MAX, r2/r7)
#define NB 8                     // batches per recurrence WG
#define NWG 8                    // recurrence WGs

// ---------- helpers ----------
__device__ __forceinline__ ushort bf16_rne(float f) {
  unsigned u = __float_as_uint(f);
  return (ushort)((u + 0x7FFFu + ((u >> 16) & 1u)) >> 16);
}
__device__ __forceinline__ float bf16_f(ushort s) {
  return __uint_as_float(((unsigned)s) << 16);
}
__device__ __forceinline__ unsigned cvt_pk_bf16(float lo, float hi) {
  unsigned r;
  asm("v_cvt_pk_bf16_f32 %0, %1, %2" : "=v"(r) : "v"(lo), "v"(hi));
  return r;
}
__device__ __forceinline__ void gll16(const void* g, void* l) {
  __builtin_amdgcn_global_load_lds((const __attribute__((address_space(1))) void*)g,
                                   (__attribute__((address_space(3))) void*)l, 16, 0, 0);
}
// tanh(a/SC) where a is pre-scaled by SC = 2*log2(e): t = 2^a; tanh = (t-1)/(t+1)
__device__ __forceinline__ float tanh_pre(float a) {
#if __has_builtin(__builtin_amdgcn_exp2f)
  float t = __builtin_amdgcn_exp2f(fminf(a, 26.0f));
#else
  float t = exp2f(fminf(a, 26.0f));
#endif
#if __has_builtin(__builtin_amdgcn_rcpf)
  return (t - 1.0f) * __builtin_amdgcn_rcpf(t + 1.0f);
#else
  return (t - 1.0f) / (t + 1.0f);
#endif
}

// ---------- fp32 -> bf16 convert (with scale) ----------
__global__ void cvt_kern(const float* __restrict__ in, ushort* __restrict__ out, long n,
                         float scale) {
  long i = ((long)blockIdx.x * blockDim.x + threadIdx.x) * 4;
  const long stride = (long)gridDim.x * blockDim.x * 4;
  for (; i < n; i += stride) {
    const float4 v = *(const float4*)(in + i);
    ushort4 o;
    o.x = bf16_rne(v.x * scale); o.y = bf16_rne(v.y * scale);
    o.z = bf16_rne(v.z * scale); o.w = bf16_rne(v.w * scale);
    *(ushort4*)(out + i) = o;
  }
}

__global__ void biascomb_kern(const float* __restrict__ a, const float* __restrict__ b,
                              float* __restrict__ o) {
  int i = threadIdx.x;
  o[i] = (a[i] + b[i]) * SC;
}

// ---------- small fp32 GEMM: C[M,N] = A[M,K] @ B[K,N], row-major ----------
__global__ __launch_bounds__(256) void f32gemm_kern(
    const float* __restrict__ A, const float* __restrict__ Bm,
    float* __restrict__ C, int M, int N, int K)
{
  __shared__ float As[16][16];
  __shared__ float Bs[16][17];
  const int tx = threadIdx.x & 15, ty = threadIdx.x >> 4;
  const int row = blockIdx.y * 16 + ty, col = blockIdx.x * 16 + tx;
  float acc = 0.0f;
  for (int k0 = 0; k0 < K; k0 += 16) {
    As[ty][tx] = A[(size_t)row * K + k0 + tx];
    Bs[ty][tx] = Bm[(size_t)(k0 + ty) * N + col];
    __syncthreads();
    #pragma unroll
    for (int kk = 0; kk < 16; ++kk) acc += As[ty][kk] * Bs[kk][tx];
    __syncthreads();
  }
  C[(size_t)row * N + col] = acc;
}

// ---------- matvec: y = M@x + b (fp32), one wave per row, shuffle reduce ----------
__global__ void matvec_kern(const float* __restrict__ Mw, const float* __restrict__ x,
                            const float* __restrict__ b, float* __restrict__ y, int R, int C) {
  const int wid = (int)((blockIdx.x * blockDim.x + threadIdx.x) >> 6);
  const int lane = threadIdx.x & 63;
  if (wid >= R) return;
  float acc = 0.0f;
  for (int k = lane; k < C; k += 64) acc += Mw[(size_t)wid * C + k] * x[k];
  #pragma unroll
  for (int off = 32; off; off >>= 1) acc += __shfl_down(acc, off, 64);
  if (lane == 0) y[wid] = acc + b[wid];
}

// ---------- GEMM: C[M,N] = A[M,K] @ Wt[N,K]^T + bias ----------
template<bool OUT_F32>
__global__ __launch_bounds__(256) void gemm_kern(
    const ushort* __restrict__ A, const ushort* __restrict__ Wt,
    const float* __restrict__ bias, void* __restrict__ out,
    int M, int N, int K)
{
  __shared__ char smem[16384];
  const int tid = threadIdx.x;
  const int lane = tid & 63, wave = tid >> 6;
  const int wm = wave >> 1, wn = wave & 1;
  const int nt = N >> 7;
  const int bm = blockIdx.x / nt, bn = blockIdx.x % nt;
  const long m0 = (long)bm * 128, n0 = (long)bn * 128;

  f32x4 acc[4][4] = {};
  const int KT = K >> 5;
  for (int kt = 0; kt < KT; ++kt) {
    #pragma unroll
    for (int i = 0; i < 4; ++i) {
      const int c = wave * 4 + i;
      const int isB = c >> 3;
      const int cc = c & 7;
      const int kgrp = cc >> 1, rhalf = cc & 1;
      const int row = rhalf * 64 + lane;
      const ushort* src = (isB ? Wt + (n0 + row) * (long)K : A + (m0 + row) * (long)K)
                          + (long)kt * 32 + kgrp * 8;
      gll16(src, smem + isB * 8192 + kgrp * 2048 + rhalf * 1024);
    }
    __syncthreads();
    const char* Ab = smem + (lane >> 4) * 2048;
    const char* Bb = smem + 8192 + (lane >> 4) * 2048;
    short8 af[4], bf[4];
    #pragma unroll
    for (int i = 0; i < 4; ++i) {
      af[i] = *(const short8*)(Ab + (wm * 64 + i * 16 + (lane & 15)) * 16);
      bf[i] = *(const short8*)(Bb + (wn * 64 + i * 16 + (lane & 15)) * 16);
    }
    #pragma unroll
    for (int mi = 0; mi < 4; ++mi)
      #pragma unroll
      for (int ni = 0; ni < 4; ++ni)
        acc[mi][ni] = __builtin_amdgcn_mfma_f32_16x16x32_bf16(af[mi], bf[ni], acc[mi][ni], 0, 0, 0);
    __syncthreads();
  }
  #pragma unroll
  for (int ni = 0; ni < 4; ++ni) {
    const long n = n0 + wn * 64 + ni * 16 + (lane & 15);
    const float bv = bias[n];
    #pragma unroll
    for (int mi = 0; mi < 4; ++mi) {
      const long mrow = m0 + wm * 64 + mi * 16 + (lane >> 4) * 4;
      #pragma unroll
      for (int r = 0; r < 4; ++r) {
        const float v = acc[mi][ni][r] + bv;
        if (OUT_F32) ((float*)out)[(mrow + r) * (long)N + n] = v;
        else         ((ushort*)out)[(mrow + r) * (long)N + n] = bf16_rne(v);
      }
    }
  }
}

// ---------- recurrence: h_t = tanh(xu_t + W h_{t-1}) (args pre-scaled by SC) ----------
// r7 structure (anchor: rec 2322us) with ONE delta: NWG 4->8, NB 16->8.
// 8 WGs x 8 batches, 512 threads = 8 waves (2/SIMD), 4 m-tiles/wave, NPIN=12.
// Lanes b>=8 mirror lanes b<8 (c = b&7): their h-LDS reads hit IDENTICAL
// addresses -> HW broadcast (free, m136) -> h-read bandwidth cost HALVES.
// Ghost MFMA cols are free (MFMA pipe ~620 of 5443 cyc). Stores guarded b<8.
// W k-slices 0..11 pinned via asm (192 regs, proven envelope); 12..15 in LDS.
// h ping-pong [2][8][1024B] (16KB); W-LDS 128KB; total 144KB.
__global__ __launch_bounds__(512, 2) void rec_kern(
    const ushort* __restrict__ XU,   // [B*S, H] bf16, SC-scaled; row = b*S + t
    const ushort* __restrict__ Wb,   // [H, H] bf16 row-major, SC-scaled
    ushort* __restrict__ Hst)        // [B*S, H] bf16 (unscaled h)
{
  extern __shared__ char smem[];     // [0,16K): h pingpong   [16K,144K): W slices 12..15
  const int tid = threadIdx.x;
  const int lane = tid & 63;
  const int wave = tid >> 6;         // 0..7
  const int b = lane & 15;
  const int hi = lane >> 4;          // 0..3
  const int c = b & 7;               // real batch col; b>=8 mirrors c
  const int bg = blockIdx.x * NB;
  const int swz = c << 4;            // r2 swizzle formula (empirically best)

  // stage W slices 12..15 -> LDS fragments [(s-12)][mt][lane*16]
  #pragma unroll
  for (int i = 0; i < 16; ++i) {
    const int ch = wave * 16 + i;          // 0..127
    const int s = 12 + (ch >> 5);
    const int mt = ch & 31;
    const ushort* src = Wb + (size_t)(mt * 16 + b) * H_ + s * 32 + hi * 8;
    gll16(src, smem + 16384 + (size_t)(s - 12) * 32768 + mt * 1024);
  }
  // zero both h buffers (h_{-1} = 0 in buf 0); 16KB via 512 threads x 32B
  {
    f32x4 zz = 0.0f;
    *(f32x4*)(smem + tid * 32) = zz;
    *(f32x4*)(smem + tid * 32 + 16) = zz;
  }
  // W registers: slices 0..11 for this wave's 4 m-tiles, pinned live via asm
  short8 wreg[4][NPIN];
  #pragma unroll
  for (int mt = 0; mt < 4; ++mt) {
    const int mtg = wave * 4 + mt;
    const ushort* wrow = Wb + (size_t)(mtg * 16 + b) * H_ + hi * 8;
    #pragma unroll
    for (int s = 0; s < NPIN; ++s)
      wreg[mt][s] = *(const short8*)(wrow + s * 32);
  }
  #pragma unroll
  for (int mt = 0; mt < 4; ++mt)
    #pragma unroll
    for (int s = 0; s < NPIN; ++s)
      asm volatile("" : "+v"(wreg[mt][s]));
  __syncthreads();

  const ushort* xup = XU + (size_t)(bg + c) * S_ * H_ + wave * 64 + hi * 4;
  ushort* hgp = Hst + (size_t)(bg + b) * S_ * H_ + wave * 64 + hi * 4;  // valid iff b<8
  const int hoff = c * 1024;                     // h row base within buffer
  const int woff = wave * 128 + hi * 8;          // epilogue LDS write base (bytes, pre-XOR)

  for (int t = 0; t < S_; ++t) {
    // issue xu loads now; consumed in the epilogue (~2k cycles later)
    uint2 xu[4];
    #pragma unroll
    for (int mt = 0; mt < 4; ++mt)
      xu[mt] = *(const uint2*)(xup + mt * 16);
    xup += H_;

    const char* hb = smem + (t & 1) * 8192 + hoff;    // h_{t-1}
    f32x4 acc[4] = {};
    #pragma unroll
    for (int s = 0; s < 16; ++s) {
      const short8 bfrag = *(const short8*)(hb + ((s * 64 + hi * 16) ^ swz));
      #pragma unroll
      for (int mt = 0; mt < 4; ++mt) {
        short8 w;
        if (s < NPIN) w = wreg[mt][s];
        else w = *(const short8*)(smem + 16384 + (s - 12) * 32768 + (wave * 4 + mt) * 1024 + lane * 16);
        acc[mt] = __builtin_amdgcn_mfma_f32_16x16x32_bf16(w, bfrag, acc[mt], 0, 0, 0);
      }
    }
    // epilogue: h_t = tanh_pre(acc + xu), cvt_pk pack; only b<8 lanes store
    char* hw = smem + ((t + 1) & 1) * 8192 + hoff;
    #pragma unroll
    for (int mt = 0; mt < 4; ++mt) {
      const float h0 = tanh_pre(acc[mt][0] + bf16_f((ushort)(xu[mt].x & 0xFFFFu)));
      const float h1 = tanh_pre(acc[mt][1] + bf16_f((ushort)(xu[mt].x >> 16)));
      const float h2 = tanh_pre(acc[mt][2] + bf16_f((ushort)(xu[mt].y & 0xFFFFu)));
      const float h3 = tanh_pre(acc[mt][3] + bf16_f((ushort)(xu[mt].y >> 16)));
      uint2 hv;
      hv.x = cvt_pk_bf16(h0, h1);
      hv.y = cvt_pk_bf16(h2, h3);
      if (b < 8) {
        *(uint2*)(hw + ((woff + mt * 32) ^ swz)) = hv;   // h for next step
        *(uint2*)(hgp + mt * 16) = hv;                   // h for head GEMM
      }
    }
    hgp += H_;
    __syncthreads();  // h_t visible (and h_{t-1} reads done) before next step
  }
}

// ---------- launcher ----------
extern "C" void kernel_launch(void* const* d_in, const int* in_sizes, int n_in,
                              void* d_out, int out_size, void* d_ws, size_t ws_size,
                              hipStream_t stream) {
  const float* x     = (const float*)d_in[0];
  const float* U_w   = (const float*)d_in[1];
  const float* U_b   = (const float*)d_in[2];
  const float* W_w   = (const float*)d_in[3];
  const float* W_b   = (const float*)d_in[4];
  const float* V_w   = (const float*)d_in[5];
  const float* V_b   = (const float*)d_in[6];
  const float* fc1_w = (const float*)d_in[7];
  const float* fc1_b = (const float*)d_in[8];
  const float* fc2_w = (const float*)d_in[9];
  const float* fc2_b = (const float*)d_in[10];
  const float* fc3_w = (const float*)d_in[11];
  const float* fc3_b = (const float*)d_in[12];

  char* ws = (char*)d_ws;
  // ws layout: [0,64M): Hst   [64M,96M): x_bf16   [128M, +~4M): weights/scratch
  ushort* Hst  = (ushort*)ws;                               // 67,108,864 B
  ushort* xb16 = (ushort*)(ws + 67108864);                  // 33,554,432 B
  char*   wb   = ws + 134217728;
  ushort* U_wb = (ushort*)wb;                    // 512*256  (SC-scaled)
  ushort* W_wb = U_wb + 131072;                  // 512*512  (SC-scaled)
  ushort* Wcb  = W_wb + 262144;                  // 256*512
  float*  C1   = (float*)(Wcb + 131072);         // 512*512 f32
  float*  C2   = C1 + 262144;                    // 512*512 f32
  float*  Wcf  = C2 + 262144;                    // 256*512 f32
  float*  cbias = Wcf + 131072;                  // 512 f32 (SC-scaled)
  float*  t1   = cbias + 512;                    // 512 f32
  float*  t2   = t1 + 512;                       // 512 f32
  float*  bc   = t2 + 512;                       // 256 f32
  ushort* bufA = (ushort*)d_out;                 // XU scratch (bf16), then fp32 out

  // bf16 staging converts (U_w, W_w, cbias pre-scaled by SC = 2*log2e)
  cvt_kern<<<2048, 256, 0, stream>>>(x, xb16, (long)M_ * I_, 1.0f);
  cvt_kern<<<128, 256, 0, stream>>>(U_w, U_wb, (long)H_ * I_, SC);
  cvt_kern<<<256, 256, 0, stream>>>(W_w, W_wb, (long)H_ * H_, SC);
  biascomb_kern<<<1, 512, 0, stream>>>(U_b, W_b, cbias);

  // fused head weights (fp32): C1 = fc1@V, C2 = fc2@C1, Wc = fc3@C2
  f32gemm_kern<<<dim3(32, 32), 256, 0, stream>>>(fc1_w, V_w, C1, H_, H_, H_);
  f32gemm_kern<<<dim3(32, 32), 256, 0, stream>>>(fc2_w, C1, C2, H_, H_, H_);
  f32gemm_kern<<<dim3(32, 16), 256, 0, stream>>>(fc3_w, C2, Wcf, O_, H_, H_);
  // bias chain: bc = fc3@(fc2@(fc1@V_b + b1) + b2) + b3  (wave-per-row matvecs)
  matvec_kern<<<128, 256, 0, stream>>>(fc1_w, V_b, fc1_b, t1, H_, H_);
  matvec_kern<<<128, 256, 0, stream>>>(fc2_w, t1, fc2_b, t2, H_, H_);
  matvec_kern<<<64, 256, 0, stream>>>(fc3_w, t2, fc3_b, bc, O_, H_);
  cvt_kern<<<128, 256, 0, stream>>>(Wcf, Wcb, (long)O_ * H_, 1.0f);

  // XU = x @ (SC*U^T) + SC*(U_b + W_b)   -> bufA (d_out as bf16 scratch)
  gemm_kern<false><<<dim3(512 * 4), 256, 0, stream>>>(xb16, U_wb, cbias, bufA, M_, H_, I_);

  // recurrence -> Hst
  hipFuncSetAttribute((const void*)rec_kern, hipFuncAttributeMaxDynamicSharedMemorySize, 147456);
  rec_kern<<<dim3(NWG), dim3(512), 147456, stream>>>(bufA, W_wb, Hst);

  // head: out = Hst @ Wc^T + bc -> d_out fp32 [B,S,O]
  gemm_kern<true><<<dim3(512 * 2), 256, 0, stream>>>(Hst, Wcb, bc, d_out, M_, O_, H_);

  (void)in_sizes; (void)n_in; (void)out_size; (void)ws_size;
}

// Round 11
// 2542.360 us; speedup vs baseline: 2.2863x; 1.1231x over previous
//
#include <hip/hip_runtime.h>
#include <hip/hip_bf16.h>

typedef __attribute__((ext_vector_type(8))) short short8;
typedef __attribute__((ext_vector_type(4))) float f32x4;

#define B_ 64
#define S_ 1024
#define I_ 256
#define H_ 512
#define O_ 256
#define M_ (B_ * S_)   // 65536 rows everywhere
#define SC 2.8853900817779268f   // 2*log2(e), folded into U_w, W_w, cbias
#define NPIN 12                  // W k-slices pinned in regs (PROVEN MAX, r2/r7)

// ---------- helpers ----------
__device__ __forceinline__ ushort bf16_rne(float f) {
  unsigned u = __float_as_uint(f);
  return (ushort)((u + 0x7FFFu + ((u >> 16) & 1u)) >> 16);
}
__device__ __forceinline__ float bf16_f(ushort s) {
  return __uint_as_float(((unsigned)s) << 16);
}
__device__ __forceinline__ unsigned cvt_pk_bf16(float lo, float hi) {
  unsigned r;
  asm("v_cvt_pk_bf16_f32 %0, %1, %2" : "=v"(r) : "v"(lo), "v"(hi));
  return r;
}
__device__ __forceinline__ void gll16(const void* g, void* l) {
  __builtin_amdgcn_global_load_lds((const __attribute__((address_space(1))) void*)g,
                                   (__attribute__((address_space(3))) void*)l, 16, 0, 0);
}
// tanh(a/SC) where a is pre-scaled by SC = 2*log2(e): t = 2^a; tanh = (t-1)/(t+1)
__device__ __forceinline__ float tanh_pre(float a) {
#if __has_builtin(__builtin_amdgcn_exp2f)
  float t = __builtin_amdgcn_exp2f(fminf(a, 26.0f));
#else
  float t = exp2f(fminf(a, 26.0f));
#endif
#if __has_builtin(__builtin_amdgcn_rcpf)
  return (t - 1.0f) * __builtin_amdgcn_rcpf(t + 1.0f);
#else
  return (t - 1.0f) / (t + 1.0f);
#endif
}

// ---------- fp32 -> bf16 convert (with scale) ----------
__global__ void cvt_kern(const float* __restrict__ in, ushort* __restrict__ out, long n,
                         float scale) {
  long i = ((long)blockIdx.x * blockDim.x + threadIdx.x) * 4;
  const long stride = (long)gridDim.x * blockDim.x * 4;
  for (; i < n; i += stride) {
    const float4 v = *(const float4*)(in + i);
    ushort4 o;
    o.x = bf16_rne(v.x * scale); o.y = bf16_rne(v.y * scale);
    o.z = bf16_rne(v.z * scale); o.w = bf16_rne(v.w * scale);
    *(ushort4*)(out + i) = o;
  }
}

__global__ void biascomb_kern(const float* __restrict__ a, const float* __restrict__ b,
                              float* __restrict__ o) {
  int i = threadIdx.x;
  o[i] = (a[i] + b[i]) * SC;
}

// ---------- small fp32 GEMM: C[M,N] = A[M,K] @ B[K,N], row-major ----------
__global__ __launch_bounds__(256) void f32gemm_kern(
    const float* __restrict__ A, const float* __restrict__ Bm,
    float* __restrict__ C, int M, int N, int K)
{
  __shared__ float As[16][16];
  __shared__ float Bs[16][17];
  const int tx = threadIdx.x & 15, ty = threadIdx.x >> 4;
  const int row = blockIdx.y * 16 + ty, col = blockIdx.x * 16 + tx;
  float acc = 0.0f;
  for (int k0 = 0; k0 < K; k0 += 16) {
    As[ty][tx] = A[(size_t)row * K + k0 + tx];
    Bs[ty][tx] = Bm[(size_t)(k0 + ty) * N + col];
    __syncthreads();
    #pragma unroll
    for (int kk = 0; kk < 16; ++kk) acc += As[ty][kk] * Bs[kk][tx];
    __syncthreads();
  }
  C[(size_t)row * N + col] = acc;
}

// ---------- matvec: y = M@x + b (fp32), one wave per row, shuffle reduce ----------
__global__ void matvec_kern(const float* __restrict__ Mw, const float* __restrict__ x,
                            const float* __restrict__ b, float* __restrict__ y, int R, int C) {
  const int wid = (int)((blockIdx.x * blockDim.x + threadIdx.x) >> 6);
  const int lane = threadIdx.x & 63;
  if (wid >= R) return;
  float acc = 0.0f;
  for (int k = lane; k < C; k += 64) acc += Mw[(size_t)wid * C + k] * x[k];
  #pragma unroll
  for (int off = 32; off; off >>= 1) acc += __shfl_down(acc, off, 64);
  if (lane == 0) y[wid] = acc + b[wid];
}

// ---------- GEMM: C[M,N] = A[M,K] @ Wt[N,K]^T + bias ----------
template<bool OUT_F32>
__global__ __launch_bounds__(256) void gemm_kern(
    const ushort* __restrict__ A, const ushort* __restrict__ Wt,
    const float* __restrict__ bias, void* __restrict__ out,
    int M, int N, int K)
{
  __shared__ char smem[16384];
  const int tid = threadIdx.x;
  const int lane = tid & 63, wave = tid >> 6;
  const int wm = wave >> 1, wn = wave & 1;
  const int nt = N >> 7;
  const int bm = blockIdx.x / nt, bn = blockIdx.x % nt;
  const long m0 = (long)bm * 128, n0 = (long)bn * 128;

  f32x4 acc[4][4] = {};
  const int KT = K >> 5;
  for (int kt = 0; kt < KT; ++kt) {
    #pragma unroll
    for (int i = 0; i < 4; ++i) {
      const int c = wave * 4 + i;
      const int isB = c >> 3;
      const int cc = c & 7;
      const int kgrp = cc >> 1, rhalf = cc & 1;
      const int row = rhalf * 64 + lane;
      const ushort* src = (isB ? Wt + (n0 + row) * (long)K : A + (m0 + row) * (long)K)
                          + (long)kt * 32 + kgrp * 8;
      gll16(src, smem + isB * 8192 + kgrp * 2048 + rhalf * 1024);
    }
    __syncthreads();
    const char* Ab = smem + (lane >> 4) * 2048;
    const char* Bb = smem + 8192 + (lane >> 4) * 2048;
    short8 af[4], bf[4];
    #pragma unroll
    for (int i = 0; i < 4; ++i) {
      af[i] = *(const short8*)(Ab + (wm * 64 + i * 16 + (lane & 15)) * 16);
      bf[i] = *(const short8*)(Bb + (wn * 64 + i * 16 + (lane & 15)) * 16);
    }
    #pragma unroll
    for (int mi = 0; mi < 4; ++mi)
      #pragma unroll
      for (int ni = 0; ni < 4; ++ni)
        acc[mi][ni] = __builtin_amdgcn_mfma_f32_16x16x32_bf16(af[mi], bf[ni], acc[mi][ni], 0, 0, 0);
    __syncthreads();
  }
  #pragma unroll
  for (int ni = 0; ni < 4; ++ni) {
    const long n = n0 + wn * 64 + ni * 16 + (lane & 15);
    const float bv = bias[n];
    #pragma unroll
    for (int mi = 0; mi < 4; ++mi) {
      const long mrow = m0 + wm * 64 + mi * 16 + (lane >> 4) * 4;
      #pragma unroll
      for (int r = 0; r < 4; ++r) {
        const float v = acc[mi][ni][r] + bv;
        if (OUT_F32) ((float*)out)[(mrow + r) * (long)N + n] = v;
        else         ((ushort*)out)[(mrow + r) * (long)N + n] = bf16_rne(v);
      }
    }
  }
}

// ---------- recurrence: h_t = tanh(xu_t + W h_{t-1}) (args pre-scaled by SC) ----------
// r7 structure (anchor: rec 2322us) with ONE delta: Hst global stores moved
// AFTER the barrier. Mechanism: __syncthreads forces vmcnt(0); in r7 the 4
// stores issue ~100cyc before the barrier -> their L2-ack (~200-400cyc) sits
// on the critical path every step. Post-barrier, they retire under the next
// step's ~5k-cyc MFMA phase and the next barrier's drain is free.
// (r5 contained this delta but bundled with the bad b<<4 swizzle (+678us,
// isolated in r6) and setprio; this is the isolation test.)
// Everything else byte-identical to r7: 4 WGs x 16 batches, 8 waves (2/SIMD),
// 4 m-tiles/wave, NPIN=12 (192 VGPR pinned, proven max), W slices 12..15 in
// LDS (128KB), h ping-pong 32KB, swz=(b&7)<<4, 1 barrier/step.
__global__ __launch_bounds__(512, 2) void rec_kern(
    const ushort* __restrict__ XU,   // [B*S, H] bf16, SC-scaled; row = b*S + t
    const ushort* __restrict__ Wb,   // [H, H] bf16 row-major, SC-scaled
    ushort* __restrict__ Hst)        // [B*S, H] bf16 (unscaled h)
{
  extern __shared__ char smem[];     // [0,32K): h pingpong   [32K, 160K): W slices 12..15
  const int tid = threadIdx.x;
  const int lane = tid & 63;
  const int wave = tid >> 6;         // 0..7
  const int b = lane & 15;
  const int hi = lane >> 4;          // 0..3
  const int bg = blockIdx.x << 4;
  const int swz = (b & 7) << 4;      // r2 swizzle (empirically best: r6)

  // stage W slices 12..15 -> LDS fragments [(s-12)][mtg][lane*16]
  #pragma unroll
  for (int i = 0; i < 16; ++i) {
    const int ch = wave * 16 + i;          // 0..127
    const int s = 12 + (ch >> 5);
    const int mt = ch & 31;
    const ushort* src = Wb + (size_t)(mt * 16 + b) * H_ + s * 32 + hi * 8;
    gll16(src, smem + 32768 + (size_t)(s - 12) * 32768 + mt * 1024);
  }
  // zero both h buffers (h_{-1} = 0 in buf 0)
  {
    f32x4 zz = 0.0f;
    *(f32x4*)(smem + tid * 64) = zz;
    *(f32x4*)(smem + tid * 64 + 16) = zz;
    *(f32x4*)(smem + tid * 64 + 32) = zz;
    *(f32x4*)(smem + tid * 64 + 48) = zz;
  }
  // W registers: slices 0..11 for this wave's 4 m-tiles, pinned live via asm
  short8 wreg[4][NPIN];
  #pragma unroll
  for (int mt = 0; mt < 4; ++mt) {
    const int mtg = wave * 4 + mt;
    const ushort* wrow = Wb + (size_t)(mtg * 16 + b) * H_ + hi * 8;
    #pragma unroll
    for (int s = 0; s < NPIN; ++s)
      wreg[mt][s] = *(const short8*)(wrow + s * 32);
  }
  #pragma unroll
  for (int mt = 0; mt < 4; ++mt)
    #pragma unroll
    for (int s = 0; s < NPIN; ++s)
      asm volatile("" : "+v"(wreg[mt][s]));
  __syncthreads();

  const ushort* xup = XU + (size_t)(bg + b) * S_ * H_ + wave * 64 + hi * 4;
  ushort* hgp = Hst + (size_t)(bg + b) * S_ * H_ + wave * 64 + hi * 4;
  const int hoff = b * 1024;                     // within h buffer
  const int woff = (wave * 128 + hi * 8);        // epilogue LDS write base (bytes, pre-XOR)

  for (int t = 0; t < S_; ++t) {
    // issue xu loads now; consumed in the epilogue (~2k cycles later)
    uint2 xu[4];
    #pragma unroll
    for (int mt = 0; mt < 4; ++mt)
      xu[mt] = *(const uint2*)(xup + mt * 16);
    xup += H_;

    const char* hb = smem + (t & 1) * 16384 + hoff;    // h_{t-1}
    f32x4 acc[4] = {};
    #pragma unroll
    for (int s = 0; s < 16; ++s) {
      const short8 bfrag = *(const short8*)(hb + ((s * 64 + hi * 16) ^ swz));
      #pragma unroll
      for (int mt = 0; mt < 4; ++mt) {
        short8 w;
        if (s < NPIN) w = wreg[mt][s];
        else w = *(const short8*)(smem + 32768 + (s - 12) * 32768 + (wave * 4 + mt) * 1024 + lane * 16);
        acc[mt] = __builtin_amdgcn_mfma_f32_16x16x32_bf16(w, bfrag, acc[mt], 0, 0, 0);
      }
    }
    // epilogue: h_t = tanh_pre(acc + xu), cvt_pk pack, LDS write (pre-barrier)
    char* hw = smem + ((t + 1) & 1) * 16384 + hoff;
    uint2 hv[4];
    #pragma unroll
    for (int mt = 0; mt < 4; ++mt) {
      const float h0 = tanh_pre(acc[mt][0] + bf16_f((ushort)(xu[mt].x & 0xFFFFu)));
      const float h1 = tanh_pre(acc[mt][1] + bf16_f((ushort)(xu[mt].x >> 16)));
      const float h2 = tanh_pre(acc[mt][2] + bf16_f((ushort)(xu[mt].y & 0xFFFFu)));
      const float h3 = tanh_pre(acc[mt][3] + bf16_f((ushort)(xu[mt].y >> 16)));
      hv[mt].x = cvt_pk_bf16(h0, h1);
      hv[mt].y = cvt_pk_bf16(h2, h3);
      *(uint2*)(hw + ((woff + mt * 32) ^ swz)) = hv[mt];   // h for next step
    }
    __syncthreads();  // h_t visible (and h_{t-1} reads done) before next step

    // global stores post-barrier: retire under next step's MFMA phase;
    // drained (for free) at the NEXT barrier, not this one.
    #pragma unroll
    for (int mt = 0; mt < 4; ++mt)
      *(uint2*)(hgp + mt * 16) = hv[mt];
    hgp += H_;
  }
}

// ---------- launcher ----------
extern "C" void kernel_launch(void* const* d_in, const int* in_sizes, int n_in,
                              void* d_out, int out_size, void* d_ws, size_t ws_size,
                              hipStream_t stream) {
  const float* x     = (const float*)d_in[0];
  const float* U_w   = (const float*)d_in[1];
  const float* U_b   = (const float*)d_in[2];
  const float* W_w   = (const float*)d_in[3];
  const float* W_b   = (const float*)d_in[4];
  const float* V_w   = (const float*)d_in[5];
  const float* V_b   = (const float*)d_in[6];
  const float* fc1_w = (const float*)d_in[7];
  const float* fc1_b = (const float*)d_in[8];
  const float* fc2_w = (const float*)d_in[9];
  const float* fc2_b = (const float*)d_in[10];
  const float* fc3_w = (const float*)d_in[11];
  const float* fc3_b = (const float*)d_in[12];

  char* ws = (char*)d_ws;
  // ws layout: [0,64M): Hst   [64M,96M): x_bf16   [128M, +~4M): weights/scratch
  ushort* Hst  = (ushort*)ws;                               // 67,108,864 B
  ushort* xb16 = (ushort*)(ws + 67108864);                  // 33,554,432 B
  char*   wb   = ws + 134217728;
  ushort* U_wb = (ushort*)wb;                    // 512*256  (SC-scaled)
  ushort* W_wb = U_wb + 131072;                  // 512*512  (SC-scaled)
  ushort* Wcb  = W_wb + 262144;                  // 256*512
  float*  C1   = (float*)(Wcb + 131072);         // 512*512 f32
  float*  C2   = C1 + 262144;                    // 512*512 f32
  float*  Wcf  = C2 + 262144;                    // 256*512 f32
  float*  cbias = Wcf + 131072;                  // 512 f32 (SC-scaled)
  float*  t1   = cbias + 512;                    // 512 f32
  float*  t2   = t1 + 512;                       // 512 f32
  float*  bc   = t2 + 512;                       // 256 f32
  ushort* bufA = (ushort*)d_out;                 // XU scratch (bf16), then fp32 out

  // bf16 staging converts (U_w, W_w, cbias pre-scaled by SC = 2*log2e)
  cvt_kern<<<2048, 256, 0, stream>>>(x, xb16, (long)M_ * I_, 1.0f);
  cvt_kern<<<128, 256, 0, stream>>>(U_w, U_wb, (long)H_ * I_, SC);
  cvt_kern<<<256, 256, 0, stream>>>(W_w, W_wb, (long)H_ * H_, SC);
  biascomb_kern<<<1, 512, 0, stream>>>(U_b, W_b, cbias);

  // fused head weights (fp32): C1 = fc1@V, C2 = fc2@C1, Wc = fc3@C2
  f32gemm_kern<<<dim3(32, 32), 256, 0, stream>>>(fc1_w, V_w, C1, H_, H_, H_);
  f32gemm_kern<<<dim3(32, 32), 256, 0, stream>>>(fc2_w, C1, C2, H_, H_, H_);
  f32gemm_kern<<<dim3(32, 16), 256, 0, stream>>>(fc3_w, C2, Wcf, O_, H_, H_);
  // bias chain: bc = fc3@(fc2@(fc1@V_b + b1) + b2) + b3  (wave-per-row matvecs)
  matvec_kern<<<128, 256, 0, stream>>>(fc1_w, V_b, fc1_b, t1, H_, H_);
  matvec_kern<<<128, 256, 0, stream>>>(fc2_w, t1, fc2_b, t2, H_, H_);
  matvec_kern<<<64, 256, 0, stream>>>(fc3_w, t2, fc3_b, bc, O_, H_);
  cvt_kern<<<128, 256, 0, stream>>>(Wcf, Wcb, (long)O_ * H_, 1.0f);

  // XU = x @ (SC*U^T) + SC*(U_b + W_b)   -> bufA (d_out as bf16 scratch)
  gemm_kern<false><<<dim3(512 * 4), 256, 0, stream>>>(xb16, U_wb, cbias, bufA, M_, H_, I_);

  // recurrence -> Hst
  hipFuncSetAttribute((const void*)rec_kern, hipFuncAttributeMaxDynamicSharedMemorySize, 163840);
  rec_kern<<<dim3(4), dim3(512), 163840, stream>>>(bufA, W_wb, Hst);

  // head: out = Hst @ Wc^T + bc -> d_out fp32 [B,S,O]
  gemm_kern<true><<<dim3(512 * 2), 256, 0, stream>>>(Hst, Wcb, bc, d_out, M_, O_, H_);

  (void)in_sizes; (void)n_in; (void)out_size; (void)ws_size;
}

// Round 12
// 2505.691 us; speedup vs baseline: 2.3198x; 1.0146x over previous
//
#include <hip/hip_runtime.h>
#include <hip/hip_bf16.h>

typedef __attribute__((ext_vector_type(8))) short short8;
typedef __attribute__((ext_vector_type(4))) float f32x4;

#define B_ 64
#define S_ 1024
#define I_ 256
#define H_ 512
#define O_ 256
#define M_ (B_ * S_)   // 65536 rows everywhere
#define SC 2.8853900817779268f   // 2*log2(e), folded into U_w, W_w, cbias
#define NPIN 12                  // W k-slices pinned in regs (PROVEN MAX, r2/r7)

// ---------- helpers ----------
__device__ __forceinline__ ushort bf16_rne(float f) {
  unsigned u = __float_as_uint(f);
  return (ushort)((u + 0x7FFFu + ((u >> 16) & 1u)) >> 16);
}
__device__ __forceinline__ float bf16_f(ushort s) {
  return __uint_as_float(((unsigned)s) << 16);
}
__device__ __forceinline__ unsigned cvt_pk_bf16(float lo, float hi) {
  unsigned r;
  asm("v_cvt_pk_bf16_f32 %0, %1, %2" : "=v"(r) : "v"(lo), "v"(hi));
  return r;
}
__device__ __forceinline__ void gll16(const void* g, void* l) {
  __builtin_amdgcn_global_load_lds((const __attribute__((address_space(1))) void*)g,
                                   (__attribute__((address_space(3))) void*)l, 16, 0, 0);
}
// tanh(a/SC) where a is pre-scaled by SC = 2*log2(e): t = 2^a; tanh = (t-1)/(t+1)
__device__ __forceinline__ float tanh_pre(float a) {
#if __has_builtin(__builtin_amdgcn_exp2f)
  float t = __builtin_amdgcn_exp2f(fminf(a, 26.0f));
#else
  float t = exp2f(fminf(a, 26.0f));
#endif
#if __has_builtin(__builtin_amdgcn_rcpf)
  return (t - 1.0f) * __builtin_amdgcn_rcpf(t + 1.0f);
#else
  return (t - 1.0f) / (t + 1.0f);
#endif
}

// ---------- fp32 -> bf16 convert (with scale) ----------
__global__ void cvt_kern(const float* __restrict__ in, ushort* __restrict__ out, long n,
                         float scale) {
  long i = ((long)blockIdx.x * blockDim.x + threadIdx.x) * 4;
  const long stride = (long)gridDim.x * blockDim.x * 4;
  for (; i < n; i += stride) {
    const float4 v = *(const float4*)(in + i);
    ushort4 o;
    o.x = bf16_rne(v.x * scale); o.y = bf16_rne(v.y * scale);
    o.z = bf16_rne(v.z * scale); o.w = bf16_rne(v.w * scale);
    *(ushort4*)(out + i) = o;
  }
}

__global__ void biascomb_kern(const float* __restrict__ a, const float* __restrict__ b,
                              float* __restrict__ o) {
  int i = threadIdx.x;
  o[i] = (a[i] + b[i]) * SC;
}

// ---------- small fp32 GEMM: C[M,N] = A[M,K] @ B[K,N], row-major ----------
__global__ __launch_bounds__(256) void f32gemm_kern(
    const float* __restrict__ A, const float* __restrict__ Bm,
    float* __restrict__ C, int M, int N, int K)
{
  __shared__ float As[16][16];
  __shared__ float Bs[16][17];
  const int tx = threadIdx.x & 15, ty = threadIdx.x >> 4;
  const int row = blockIdx.y * 16 + ty, col = blockIdx.x * 16 + tx;
  float acc = 0.0f;
  for (int k0 = 0; k0 < K; k0 += 16) {
    As[ty][tx] = A[(size_t)row * K + k0 + tx];
    Bs[ty][tx] = Bm[(size_t)(k0 + ty) * N + col];
    __syncthreads();
    #pragma unroll
    for (int kk = 0; kk < 16; ++kk) acc += As[ty][kk] * Bs[kk][tx];
    __syncthreads();
  }
  C[(size_t)row * N + col] = acc;
}

// ---------- matvec: y = M@x + b (fp32), one wave per row, shuffle reduce ----------
__global__ void matvec_kern(const float* __restrict__ Mw, const float* __restrict__ x,
                            const float* __restrict__ b, float* __restrict__ y, int R, int C) {
  const int wid = (int)((blockIdx.x * blockDim.x + threadIdx.x) >> 6);
  const int lane = threadIdx.x & 63;
  if (wid >= R) return;
  float acc = 0.0f;
  for (int k = lane; k < C; k += 64) acc += Mw[(size_t)wid * C + k] * x[k];
  #pragma unroll
  for (int off = 32; off; off >>= 1) acc += __shfl_down(acc, off, 64);
  if (lane == 0) y[wid] = acc + b[wid];
}

// ---------- GEMM: C[M,N] = A[M,K] @ Wt[N,K]^T + bias ----------
template<bool OUT_F32>
__global__ __launch_bounds__(256) void gemm_kern(
    const ushort* __restrict__ A, const ushort* __restrict__ Wt,
    const float* __restrict__ bias, void* __restrict__ out,
    int M, int N, int K)
{
  __shared__ char smem[16384];
  const int tid = threadIdx.x;
  const int lane = tid & 63, wave = tid >> 6;
  const int wm = wave >> 1, wn = wave & 1;
  const int nt = N >> 7;
  const int bm = blockIdx.x / nt, bn = blockIdx.x % nt;
  const long m0 = (long)bm * 128, n0 = (long)bn * 128;

  f32x4 acc[4][4] = {};
  const int KT = K >> 5;
  for (int kt = 0; kt < KT; ++kt) {
    #pragma unroll
    for (int i = 0; i < 4; ++i) {
      const int c = wave * 4 + i;
      const int isB = c >> 3;
      const int cc = c & 7;
      const int kgrp = cc >> 1, rhalf = cc & 1;
      const int row = rhalf * 64 + lane;
      const ushort* src = (isB ? Wt + (n0 + row) * (long)K : A + (m0 + row) * (long)K)
                          + (long)kt * 32 + kgrp * 8;
      gll16(src, smem + isB * 8192 + kgrp * 2048 + rhalf * 1024);
    }
    __syncthreads();
    const char* Ab = smem + (lane >> 4) * 2048;
    const char* Bb = smem + 8192 + (lane >> 4) * 2048;
    short8 af[4], bf[4];
    #pragma unroll
    for (int i = 0; i < 4; ++i) {
      af[i] = *(const short8*)(Ab + (wm * 64 + i * 16 + (lane & 15)) * 16);
      bf[i] = *(const short8*)(Bb + (wn * 64 + i * 16 + (lane & 15)) * 16);
    }
    #pragma unroll
    for (int mi = 0; mi < 4; ++mi)
      #pragma unroll
      for (int ni = 0; ni < 4; ++ni)
        acc[mi][ni] = __builtin_amdgcn_mfma_f32_16x16x32_bf16(af[mi], bf[ni], acc[mi][ni], 0, 0, 0);
    __syncthreads();
  }
  #pragma unroll
  for (int ni = 0; ni < 4; ++ni) {
    const long n = n0 + wn * 64 + ni * 16 + (lane & 15);
    const float bv = bias[n];
    #pragma unroll
    for (int mi = 0; mi < 4; ++mi) {
      const long mrow = m0 + wm * 64 + mi * 16 + (lane >> 4) * 4;
      #pragma unroll
      for (int r = 0; r < 4; ++r) {
        const float v = acc[mi][ni][r] + bv;
        if (OUT_F32) ((float*)out)[(mrow + r) * (long)N + n] = v;
        else         ((ushort*)out)[(mrow + r) * (long)N + n] = bf16_rne(v);
      }
    }
  }
}

// ---------- recurrence: h_t = tanh(xu_t + W h_{t-1}) (args pre-scaled by SC) ----------
// FINAL = round-7 kernel verbatim (best measured: rec 2322us, total 2503us).
// 4 WGs x 16 batches, 512 threads = 8 waves (2/SIMD), 4 m-tiles/wave.
// W k-slices 0..11 pinned via asm (192 regs -> compiler places in AGPRs,
// MFMA reads them directly; proven max), slices 12..15 in LDS (128KB).
// h ping-pong [2][16][512] bf16 (32KB), swz=(b&7)<<4; 1 barrier/step;
// stores pre-barrier. Single-delta ledger (r3-r11) proves each alternative
// (1-wave/SIMD, NPIN 9/14, L2-stream, b<<4 swizzle, NB=8, store-post-barrier)
// regresses or is neutral.
__global__ __launch_bounds__(512, 2) void rec_kern(
    const ushort* __restrict__ XU,   // [B*S, H] bf16, SC-scaled; row = b*S + t
    const ushort* __restrict__ Wb,   // [H, H] bf16 row-major, SC-scaled
    ushort* __restrict__ Hst)        // [B*S, H] bf16 (unscaled h)
{
  extern __shared__ char smem[];     // [0,32K): h pingpong   [32K, 160K): W slices 12..15
  const int tid = threadIdx.x;
  const int lane = tid & 63;
  const int wave = tid >> 6;         // 0..7
  const int b = lane & 15;
  const int hi = lane >> 4;          // 0..3
  const int bg = blockIdx.x << 4;
  const int swz = (b & 7) << 4;      // r2 swizzle (empirically best: r6)

  // stage W slices 12..15 -> LDS fragments [(s-12)][mtg][lane*16]
  #pragma unroll
  for (int i = 0; i < 16; ++i) {
    const int ch = wave * 16 + i;          // 0..127
    const int s = 12 + (ch >> 5);
    const int mt = ch & 31;
    const ushort* src = Wb + (size_t)(mt * 16 + b) * H_ + s * 32 + hi * 8;
    gll16(src, smem + 32768 + (size_t)(s - 12) * 32768 + mt * 1024);
  }
  // zero both h buffers (h_{-1} = 0 in buf 0)
  {
    f32x4 zz = 0.0f;
    *(f32x4*)(smem + tid * 64) = zz;
    *(f32x4*)(smem + tid * 64 + 16) = zz;
    *(f32x4*)(smem + tid * 64 + 32) = zz;
    *(f32x4*)(smem + tid * 64 + 48) = zz;
  }
  // W registers: slices 0..11 for this wave's 4 m-tiles, pinned live via asm
  short8 wreg[4][NPIN];
  #pragma unroll
  for (int mt = 0; mt < 4; ++mt) {
    const int mtg = wave * 4 + mt;
    const ushort* wrow = Wb + (size_t)(mtg * 16 + b) * H_ + hi * 8;
    #pragma unroll
    for (int s = 0; s < NPIN; ++s)
      wreg[mt][s] = *(const short8*)(wrow + s * 32);
  }
  #pragma unroll
  for (int mt = 0; mt < 4; ++mt)
    #pragma unroll
    for (int s = 0; s < NPIN; ++s)
      asm volatile("" : "+v"(wreg[mt][s]));
  __syncthreads();

  const ushort* xup = XU + (size_t)(bg + b) * S_ * H_ + wave * 64 + hi * 4;
  ushort* hgp = Hst + (size_t)(bg + b) * S_ * H_ + wave * 64 + hi * 4;
  const int hoff = b * 1024;                     // within h buffer
  const int woff = (wave * 128 + hi * 8);        // epilogue LDS write base (bytes, pre-XOR)

  for (int t = 0; t < S_; ++t) {
    // issue xu loads now; consumed in the epilogue (~2k cycles later)
    uint2 xu[4];
    #pragma unroll
    for (int mt = 0; mt < 4; ++mt)
      xu[mt] = *(const uint2*)(xup + mt * 16);
    xup += H_;

    const char* hb = smem + (t & 1) * 16384 + hoff;    // h_{t-1}
    f32x4 acc[4] = {};
    #pragma unroll
    for (int s = 0; s < 16; ++s) {
      const short8 bfrag = *(const short8*)(hb + ((s * 64 + hi * 16) ^ swz));
      #pragma unroll
      for (int mt = 0; mt < 4; ++mt) {
        short8 w;
        if (s < NPIN) w = wreg[mt][s];
        else w = *(const short8*)(smem + 32768 + (s - 12) * 32768 + (wave * 4 + mt) * 1024 + lane * 16);
        acc[mt] = __builtin_amdgcn_mfma_f32_16x16x32_bf16(w, bfrag, acc[mt], 0, 0, 0);
      }
    }
    // epilogue: h_t = tanh_pre(acc + xu), cvt_pk pack, LDS + global store
    char* hw = smem + ((t + 1) & 1) * 16384 + hoff;
    #pragma unroll
    for (int mt = 0; mt < 4; ++mt) {
      const float h0 = tanh_pre(acc[mt][0] + bf16_f((ushort)(xu[mt].x & 0xFFFFu)));
      const float h1 = tanh_pre(acc[mt][1] + bf16_f((ushort)(xu[mt].x >> 16)));
      const float h2 = tanh_pre(acc[mt][2] + bf16_f((ushort)(xu[mt].y & 0xFFFFu)));
      const float h3 = tanh_pre(acc[mt][3] + bf16_f((ushort)(xu[mt].y >> 16)));
      uint2 hv;
      hv.x = cvt_pk_bf16(h0, h1);
      hv.y = cvt_pk_bf16(h2, h3);
      *(uint2*)(hw + ((woff + mt * 32) ^ swz)) = hv;   // h for next step
      *(uint2*)(hgp + mt * 16) = hv;                   // h for head GEMM
    }
    hgp += H_;
    __syncthreads();  // h_t visible (and h_{t-1} reads done) before next step
  }
}

// ---------- launcher ----------
extern "C" void kernel_launch(void* const* d_in, const int* in_sizes, int n_in,
                              void* d_out, int out_size, void* d_ws, size_t ws_size,
                              hipStream_t stream) {
  const float* x     = (const float*)d_in[0];
  const float* U_w   = (const float*)d_in[1];
  const float* U_b   = (const float*)d_in[2];
  const float* W_w   = (const float*)d_in[3];
  const float* W_b   = (const float*)d_in[4];
  const float* V_w   = (const float*)d_in[5];
  const float* V_b   = (const float*)d_in[6];
  const float* fc1_w = (const float*)d_in[7];
  const float* fc1_b = (const float*)d_in[8];
  const float* fc2_w = (const float*)d_in[9];
  const float* fc2_b = (const float*)d_in[10];
  const float* fc3_w = (const float*)d_in[11];
  const float* fc3_b = (const float*)d_in[12];

  char* ws = (char*)d_ws;
  // ws layout: [0,64M): Hst   [64M,96M): x_bf16   [128M, +~4M): weights/scratch
  ushort* Hst  = (ushort*)ws;                               // 67,108,864 B
  ushort* xb16 = (ushort*)(ws + 67108864);                  // 33,554,432 B
  char*   wb   = ws + 134217728;
  ushort* U_wb = (ushort*)wb;                    // 512*256  (SC-scaled)
  ushort* W_wb = U_wb + 131072;                  // 512*512  (SC-scaled)
  ushort* Wcb  = W_wb + 262144;                  // 256*512
  float*  C1   = (float*)(Wcb + 131072);         // 512*512 f32
  float*  C2   = C1 + 262144;                    // 512*512 f32
  float*  Wcf  = C2 + 262144;                    // 256*512 f32
  float*  cbias = Wcf + 131072;                  // 512 f32 (SC-scaled)
  float*  t1   = cbias + 512;                    // 512 f32
  float*  t2   = t1 + 512;                       // 512 f32
  float*  bc   = t2 + 512;                       // 256 f32
  ushort* bufA = (ushort*)d_out;                 // XU scratch (bf16), then fp32 out

  // bf16 staging converts (U_w, W_w, cbias pre-scaled by SC = 2*log2e)
  cvt_kern<<<2048, 256, 0, stream>>>(x, xb16, (long)M_ * I_, 1.0f);
  cvt_kern<<<128, 256, 0, stream>>>(U_w, U_wb, (long)H_ * I_, SC);
  cvt_kern<<<256, 256, 0, stream>>>(W_w, W_wb, (long)H_ * H_, SC);
  biascomb_kern<<<1, 512, 0, stream>>>(U_b, W_b, cbias);

  // fused head weights (fp32): C1 = fc1@V, C2 = fc2@C1, Wc = fc3@C2
  f32gemm_kern<<<dim3(32, 32), 256, 0, stream>>>(fc1_w, V_w, C1, H_, H_, H_);
  f32gemm_kern<<<dim3(32, 32), 256, 0, stream>>>(fc2_w, C1, C2, H_, H_, H_);
  f32gemm_kern<<<dim3(32, 16), 256, 0, stream>>>(fc3_w, C2, Wcf, O_, H_, H_);
  // bias chain: bc = fc3@(fc2@(fc1@V_b + b1) + b2) + b3  (wave-per-row matvecs)
  matvec_kern<<<128, 256, 0, stream>>>(fc1_w, V_b, fc1_b, t1, H_, H_);
  matvec_kern<<<128, 256, 0, stream>>>(fc2_w, t1, fc2_b, t2, H_, H_);
  matvec_kern<<<64, 256, 0, stream>>>(fc3_w, t2, fc3_b, bc, O_, H_);
  cvt_kern<<<128, 256, 0, stream>>>(Wcf, Wcb, (long)O_ * H_, 1.0f);

  // XU = x @ (SC*U^T) + SC*(U_b + W_b)   -> bufA (d_out as bf16 scratch)
  gemm_kern<false><<<dim3(512 * 4), 256, 0, stream>>>(xb16, U_wb, cbias, bufA, M_, H_, I_);

  // recurrence -> Hst
  hipFuncSetAttribute((const void*)rec_kern, hipFuncAttributeMaxDynamicSharedMemorySize, 163840);
  rec_kern<<<dim3(4), dim3(512), 163840, stream>>>(bufA, W_wb, Hst);

  // head: out = Hst @ Wc^T + bc -> d_out fp32 [B,S,O]
  gemm_kern<true><<<dim3(512 * 2), 256, 0, stream>>>(Hst, Wcb, bc, d_out, M_, O_, H_);

  (void)in_sizes; (void)n_in; (void)out_size; (void)ws_size;
}